// Round 3
// baseline (1159.057 us; speedup 1.0000x reference)
//
#include <hip/hip_runtime.h>
#include <hip/hip_bf16.h>

#define BB 32
#define LL 200
#define DD 768
#define SS 1556

typedef __attribute__((ext_vector_type(8))) short bf16x8;   // 8 bf16 = 4 VGPRs (MFMA A/B frag)
typedef __attribute__((ext_vector_type(4))) float floatx4;  // MFMA C/D frag

__device__ __forceinline__ float bf2f(ushort u){
    union { unsigned int i; float f; } v; v.i = ((unsigned int)u) << 16; return v.f;
}
__device__ __forceinline__ ushort f2bf(float f){
    union { float f; unsigned int i; } v; v.f = f;
    unsigned int x = v.i;
    return (ushort)((x + 0x7FFFu + ((x >> 16) & 1u)) >> 16);  // RNE, inputs finite
}

// ---------------------------------------------------------------------------
// Kernel 0: dtype detector. For true-bf16 data the LOW ushort of each 32-bit
// word is a bf16 with exponent in a sane range (~[117,130] for N(0,1) feats).
// For float32 data the low 16 bits are uniform mantissa bits (~20% hit rate).
// flag=1 -> bf16, flag=0 -> float32.
// ---------------------------------------------------------------------------
__global__ void detect_kernel(const unsigned int* __restrict__ feat_raw, int* __restrict__ flag){
    __shared__ int cnt_s;
    if (threadIdx.x == 0) cnt_s = 0;
    __syncthreads();
    int c = 0;
    for (int i = threadIdx.x; i < 4096; i += 256){
        unsigned int w = feat_raw[i];
        unsigned int e = (w >> 7) & 0xFFu;      // exponent of low-half bf16
        if (e >= 100u && e <= 150u) c++;
    }
    atomicAdd(&cnt_s, c);
    __syncthreads();
    if (threadIdx.x == 0) *flag = (cnt_s > 2457) ? 1 : 0;   // >60% sane -> bf16
}

// ---------------------------------------------------------------------------
// Kernel 1: per-batch span offsets. offs[b][0..8]; counts[k] = max(n-k-2, 0).
// ---------------------------------------------------------------------------
__global__ void offs_kernel(const int* __restrict__ mask, int* __restrict__ offs){
    int b = blockIdx.x;
    int lane = threadIdx.x;
    int s = 0;
    for (int i = lane; i < LL; i += 64) s += mask[b*LL + i];
    #pragma unroll
    for (int d = 32; d > 0; d >>= 1) s += __shfl_down(s, d, 64);
    if (lane == 0){
        int n = s, cum = 0;
        offs[b*9 + 0] = 0;
        for (int j = 0; j < 8; ++j){
            int c = n - j - 2; if (c < 0) c = 0;
            cum += c;
            offs[b*9 + j + 1] = cum;
        }
    }
}

// ---------------------------------------------------------------------------
// Kernel 2 (per conv width kk): repack w_kk [768][768][kk] (O,I,T) into bf16
// Bp_kk[jb][o][jj] with j = jb*8+jj = t*768+i  -> MFMA B-frag = one 16B load.
// Bias stored as float in biasF (block 0 only). Stage-in converts if fp32.
// ---------------------------------------------------------------------------
__global__ void repack_kernel(const void* __restrict__ w, const void* __restrict__ bvec,
                              ushort* __restrict__ Bp, float* __restrict__ biasF,
                              int kkidx, const int* __restrict__ flag){
    const int bfm = *flag;
    const int kk = kkidx + 2;
    extern __shared__ ushort lds[];
    const int tid = threadIdx.x;
    const int ob  = blockIdx.x;           // 0..191, 4 output channels each
    const int rowlen = DD * kk;
    const int nelem  = 4 * rowlen;

    if (bfm){
        const ushort* src = (const ushort*)w + (size_t)ob * nelem;
        const int nch = nelem >> 3;
        for (int c = tid; c < nch; c += 256)
            __builtin_memcpy(lds + c*8, src + c*8, 16);
        if (ob == 0)
            for (int i = tid; i < DD; i += 256) biasF[kkidx*DD + i] = bf2f(((const ushort*)bvec)[i]);
    } else {
        const float* src = (const float*)w + (size_t)ob * nelem;
        const int nch = nelem >> 2;       // 16B float4 chunks
        for (int c = tid; c < nch; c += 256){
            float t4[4];
            __builtin_memcpy(t4, src + c*4, 16);
            #pragma unroll
            for (int j2 = 0; j2 < 4; ++j2) lds[c*4 + j2] = f2bf(t4[j2]);
        }
        if (ob == 0)
            for (int i = tid; i < DD; i += 256) biasF[kkidx*DD + i] = ((const float*)bvec)[i];
    }
    __syncthreads();

    const int total = 96 * kk * 4;        // jb-planes * 4 local channels
    for (int c = tid; c < total; c += 256){
        int jb = c >> 2, ol = c & 3;
        int j0 = jb * 8;
        int t  = j0 / 768;
        int i0 = j0 - t * 768;            // block of 8 never straddles t
        ushort tmp[8];
        #pragma unroll
        for (int jj = 0; jj < 8; ++jj)
            tmp[jj] = lds[ol*rowlen + (i0 + jj)*kk + t];
        int o = ob*4 + ol;
        __builtin_memcpy(Bp + (size_t)jb*6144 + (size_t)o*8, tmp, 16);
    }
}

// ---------------------------------------------------------------------------
// Kernel 2b: features -> bf16 A-source buffer (passthrough copy if already bf16).
// ---------------------------------------------------------------------------
__global__ void cvtA_kernel(const void* __restrict__ feat, ushort* __restrict__ featbf,
                            const int* __restrict__ flag){
    const int bfm = *flag;
    int idx = blockIdx.x*256 + threadIdx.x;       // one 8-element chunk each
    const int TOT = BB*LL*DD/8;                    // 614400
    if (idx >= TOT) return;
    if (bfm){
        __builtin_memcpy(featbf + (size_t)idx*8, (const ushort*)feat + (size_t)idx*8, 16);
    } else {
        float t8[8];
        __builtin_memcpy(t8,     (const float*)feat + (size_t)idx*8,     16);
        __builtin_memcpy(t8 + 4, (const float*)feat + (size_t)idx*8 + 4, 16);
        ushort o8[8];
        #pragma unroll
        for (int j = 0; j < 8; ++j) o8[j] = f2bf(t8[j]);
        __builtin_memcpy(featbf + (size_t)idx*8, o8, 16);
    }
}

// ---------------------------------------------------------------------------
// Kernel 3: unigram copy (exact passthrough in native dtype), zero invalid
// slots, valid flags. One thread per 16B(fp32)/pair chunk; c in [0,192).
// ---------------------------------------------------------------------------
__global__ void fill_kernel(const void* __restrict__ feat, const int* __restrict__ offs,
                            void* __restrict__ out, const int* __restrict__ flag){
    const int bfm = *flag;
    int idx = blockIdx.x*256 + threadIdx.x;
    const int TOT = BB*SS*192;
    if (idx >= TOT) return;
    int b = idx / (SS*192);
    int r = idx - b*(SS*192);
    int s = r / 192;
    int c = r - s*192;
    int c0  = offs[b*9 + 1];  // unigram count
    int tot = offs[b*9 + 8];  // total valid spans
    if (bfm){
        if (c < 96){
            ushort* dst = (ushort*)out + ((size_t)b*SS + s)*768 + c*8;
            if (s < c0){
                const ushort* srcp = (const ushort*)feat + ((size_t)b*LL + s + 1)*768 + c*8;
                __builtin_memcpy(dst, srcp, 16);
            } else if (s >= tot){
                const ushort z[8] = {0,0,0,0,0,0,0,0};
                __builtin_memcpy(dst, z, 16);
            }
        }
        if (c == 0)
            ((ushort*)out)[(size_t)BB*SS*768 + (size_t)b*SS + s] = (s < tot) ? (ushort)0x3F80 : (ushort)0;
    } else {
        float* dst = (float*)out + ((size_t)b*SS + s)*768 + c*4;
        if (s < c0){
            const float* srcp = (const float*)feat + ((size_t)b*LL + s + 1)*768 + c*4;
            __builtin_memcpy(dst, srcp, 16);
        } else if (s >= tot){
            const float z[4] = {0.f,0.f,0.f,0.f};
            __builtin_memcpy(dst, z, 16);
        }
        if (c == 0)
            ((float*)out)[(size_t)BB*SS*768 + (size_t)b*SS + s] = (s < tot) ? 1.0f : 0.0f;
    }
}

// ---------------------------------------------------------------------------
// Kernel 4: fused conv-as-GEMM with scatter into packed span slots.
// A from featbf (bf16, implicit im2col: contiguous rows), B from repacked Bp.
// Epilogue stores in the detected output dtype; bias folded into acc init.
// ---------------------------------------------------------------------------
__global__ __launch_bounds__(256) void conv_gemm(const ushort* __restrict__ featbf,
                                                 const ushort* __restrict__ Bp,
                                                 const float* __restrict__ biasF,
                                                 const int* __restrict__ offs,
                                                 void* __restrict__ out,
                                                 const int* __restrict__ flag){
    const int PRE[7] = {0, 2, 5, 9, 14, 20, 27};
    const int bfm = *flag;
    const int kkidx = blockIdx.y;
    const int kk = kkidx + 2;
    const int b = blockIdx.z;
    const int off_j = offs[b*9 + kk - 1];
    const int cnt   = offs[b*9 + kk] - off_j;
    const int mt = blockIdx.x / 12;
    const int nt = blockIdx.x - mt*12;
    const int m0 = mt * 64;
    if (m0 >= cnt) return;
    const int n0 = nt * 64;

    const int tid  = threadIdx.x;
    const int wv   = tid >> 6;
    const int lane = tid & 63;
    const int quad = lane >> 4;
    const int l15  = lane & 15;

    int row  = m0 + wv*16 + l15;
    int arow = row < cnt ? row : cnt - 1;          // clamp keeps reads in-bounds

    const ushort* Aptr = featbf + ((size_t)b*LL + arow + 1)*768 + quad*8;
    const ushort* Bptr = Bp + (size_t)PRE[kkidx]*589824
                            + (size_t)quad*6144 + (size_t)(n0 + l15)*8;

    floatx4 acc[4];
    #pragma unroll
    for (int cg = 0; cg < 4; ++cg){
        float bv = biasF[kkidx*768 + n0 + cg*16 + l15];
        acc[cg][0] = bv; acc[cg][1] = bv; acc[cg][2] = bv; acc[cg][3] = bv;
    }

    const int steps = kk * 24;                     // Ktot / 32
    #pragma unroll 2
    for (int s = 0; s < steps; ++s){
        bf16x8 a;
        __builtin_memcpy(&a, Aptr, 16);
        #pragma unroll
        for (int cg = 0; cg < 4; ++cg){
            bf16x8 bfr;
            __builtin_memcpy(&bfr, Bptr + cg*128, 16);
            acc[cg] = __builtin_amdgcn_mfma_f32_16x16x32_bf16(a, bfr, acc[cg], 0, 0, 0);
        }
        Aptr += 32;        // K advances 32 bf16
        Bptr += 24576;     // 4 jb-planes of 6144
    }

    const int rbase = m0 + wv*16 + quad*4;
    if (bfm){
        ushort* outh = (ushort*)out;
        #pragma unroll
        for (int cg = 0; cg < 4; ++cg)
            #pragma unroll
            for (int rr = 0; rr < 4; ++rr){
                int grow = rbase + rr;
                if (grow < cnt)
                    outh[((size_t)b*SS + off_j + grow)*768 + n0 + cg*16 + l15] = f2bf(acc[cg][rr]);
            }
    } else {
        float* outf = (float*)out;
        #pragma unroll
        for (int cg = 0; cg < 4; ++cg)
            #pragma unroll
            for (int rr = 0; rr < 4; ++rr){
                int grow = rbase + rr;
                if (grow < cnt)
                    outf[((size_t)b*SS + off_j + grow)*768 + n0 + cg*16 + l15] = acc[cg][rr];
            }
    }
}

// ---------------------------------------------------------------------------
// Fallback (workspace too small for repack): B-fragments gathered directly
// from raw w [O][I][T], A converted in-loop. Slow but correct.
// ---------------------------------------------------------------------------
__global__ __launch_bounds__(256) void conv_gemm_direct(const void* __restrict__ feat,
        const int* __restrict__ offs, void* __restrict__ out, const int* __restrict__ flag,
        const void* w2, const void* w3, const void* w4, const void* w5,
        const void* w6, const void* w7, const void* w8,
        const void* b2, const void* b3, const void* b4, const void* b5,
        const void* b6, const void* b7, const void* b8){
    const int bfm = *flag;
    const int kkidx = blockIdx.y;
    const int kk = kkidx + 2;
    const int b = blockIdx.z;
    const void* w  = kkidx==0?w2:kkidx==1?w3:kkidx==2?w4:kkidx==3?w5:kkidx==4?w6:kkidx==5?w7:w8;
    const void* bv = kkidx==0?b2:kkidx==1?b3:kkidx==2?b4:kkidx==3?b5:kkidx==4?b6:kkidx==5?b7:b8;

    const int off_j = offs[b*9 + kk - 1];
    const int cnt   = offs[b*9 + kk] - off_j;
    const int mt = blockIdx.x / 12;
    const int nt = blockIdx.x - mt*12;
    const int m0 = mt * 64;
    if (m0 >= cnt) return;
    const int n0 = nt * 64;

    const int tid  = threadIdx.x;
    const int wv   = tid >> 6;
    const int lane = tid & 63;
    const int quad = lane >> 4;
    const int l15  = lane & 15;

    int row  = m0 + wv*16 + l15;
    int arow = row < cnt ? row : cnt - 1;
    const size_t abase = ((size_t)b*LL + arow + 1)*768 + quad*8;

    floatx4 acc[4];
    #pragma unroll
    for (int cg = 0; cg < 4; ++cg){
        float bb = bfm ? bf2f(((const ushort*)bv)[n0 + cg*16 + l15])
                       : ((const float*)bv)[n0 + cg*16 + l15];
        acc[cg][0] = bb; acc[cg][1] = bb; acc[cg][2] = bb; acc[cg][3] = bb;
    }

    const int steps = kk * 24;
    for (int s = 0; s < steps; ++s){
        bf16x8 a;
        if (bfm){
            __builtin_memcpy(&a, (const ushort*)feat + abase + s*32, 16);
        } else {
            float t8[8];
            __builtin_memcpy(t8,     (const float*)feat + abase + s*32,     16);
            __builtin_memcpy(t8 + 4, (const float*)feat + abase + s*32 + 4, 16);
            ushort o8[8];
            #pragma unroll
            for (int j = 0; j < 8; ++j) o8[j] = f2bf(t8[j]);
            __builtin_memcpy(&a, o8, 16);
        }
        int j0 = s*32 + quad*8;
        int t  = j0 / 768;
        int i0 = j0 - t*768;
        #pragma unroll
        for (int cg = 0; cg < 4; ++cg){
            int o = n0 + cg*16 + l15;
            size_t wbase = (size_t)o*(DD*kk) + (size_t)i0*kk + t;
            ushort tmp[8];
            if (bfm){
                const ushort* wp = (const ushort*)w + wbase;
                #pragma unroll
                for (int jj = 0; jj < 8; ++jj) tmp[jj] = wp[(size_t)jj*kk];
            } else {
                const float* wp = (const float*)w + wbase;
                #pragma unroll
                for (int jj = 0; jj < 8; ++jj) tmp[jj] = f2bf(wp[(size_t)jj*kk]);
            }
            bf16x8 bfr;
            __builtin_memcpy(&bfr, tmp, 16);
            acc[cg] = __builtin_amdgcn_mfma_f32_16x16x32_bf16(a, bfr, acc[cg], 0, 0, 0);
        }
    }

    const int rbase = m0 + wv*16 + quad*4;
    if (bfm){
        ushort* outh = (ushort*)out;
        #pragma unroll
        for (int cg = 0; cg < 4; ++cg)
            #pragma unroll
            for (int rr = 0; rr < 4; ++rr){
                int grow = rbase + rr;
                if (grow < cnt)
                    outh[((size_t)b*SS + off_j + grow)*768 + n0 + cg*16 + l15] = f2bf(acc[cg][rr]);
            }
    } else {
        float* outf = (float*)out;
        #pragma unroll
        for (int cg = 0; cg < 4; ++cg)
            #pragma unroll
            for (int rr = 0; rr < 4; ++rr){
                int grow = rbase + rr;
                if (grow < cnt)
                    outf[((size_t)b*SS + off_j + grow)*768 + n0 + cg*16 + l15] = acc[cg][rr];
            }
    }
}

// ---------------------------------------------------------------------------
extern "C" void kernel_launch(void* const* d_in, const int* in_sizes, int n_in,
                              void* d_out, int out_size, void* d_ws, size_t ws_size,
                              hipStream_t stream) {
    const void* feat = d_in[0];
    const int*  mask = (const int*)d_in[1];
    // d_in[2] = span_mask (unused: all ones, only its shape matters)

    const void* w[7]  = {0,0,0,0,0,0,0};
    const void* bs[7] = {0,0,0,0,0,0,0};
    int bi = 0;
    for (int i = 3; i < n_in; ++i){
        if (in_sizes[i] == 768){
            if (bi < 7) bs[bi++] = d_in[i];
        } else {
            int kk = in_sizes[i] / 589824;          // 768*768
            if (kk >= 2 && kk <= 8) w[kk-2] = d_in[i];
        }
    }

    // ws layout: flag @0 | offs @64 | biasF @4096 | featbf @32768 | Bp @9,863,168
    char* ws = (char*)d_ws;
    int*    flag    = (int*)ws;
    int*    offs    = (int*)(ws + 64);
    float*  biasF   = (float*)(ws + 4096);
    ushort* featbf  = (ushort*)(ws + 32768);
    ushort* Bp      = (ushort*)(ws + 9863168);
    const size_t FULL_BYTES = 9863168ull + 41287680ull;   // ~51.2 MB
    const bool use_full = ws_size >= FULL_BYTES;

    hipLaunchKernelGGL(detect_kernel, dim3(1), dim3(256), 0, stream,
                       (const unsigned int*)feat, flag);
    hipLaunchKernelGGL(offs_kernel, dim3(BB), dim3(64), 0, stream, mask, offs);

    if (use_full){
        const size_t PRE[7] = {0, 2, 5, 9, 14, 20, 27};
        for (int kkidx = 0; kkidx < 7; ++kkidx){
            int kk = kkidx + 2;
            hipLaunchKernelGGL(repack_kernel, dim3(192), dim3(256), 4*DD*kk*2, stream,
                               w[kkidx], bs[kkidx], Bp + PRE[kkidx]*589824, biasF, kkidx, flag);
        }
        hipLaunchKernelGGL(cvtA_kernel, dim3(2400), dim3(256), 0, stream, feat, featbf, flag);
    }

    hipLaunchKernelGGL(fill_kernel, dim3((BB*SS*192 + 255)/256), dim3(256), 0, stream,
                       feat, offs, d_out, flag);

    if (use_full){
        hipLaunchKernelGGL(conv_gemm, dim3(48, 7, BB), dim3(256), 0, stream,
                           featbf, Bp, biasF, offs, d_out, flag);
    } else {
        hipLaunchKernelGGL(conv_gemm_direct, dim3(48, 7, BB), dim3(256), 0, stream,
                           feat, offs, d_out, flag,
                           w[0], w[1], w[2], w[3], w[4], w[5], w[6],
                           bs[0], bs[1], bs[2], bs[3], bs[4], bs[5], bs[6]);
    }
}

// Round 4
// 686.827 us; speedup vs baseline: 1.6876x; 1.6876x over previous
//
#include <hip/hip_runtime.h>
#include <hip/hip_bf16.h>

#define BB 32
#define LL 200
#define DD 768
#define SS 1556
#define MAXM 6400   // per-kk flattened row capacity (32 * (199-kk) < 6400)

typedef __attribute__((ext_vector_type(8))) short bf16x8;   // 8 bf16 = 4 VGPRs (MFMA A/B frag)
typedef __attribute__((ext_vector_type(4))) float floatx4;  // MFMA C/D frag

__device__ __forceinline__ float bf2f(ushort u){
    union { unsigned int i; float f; } v; v.i = ((unsigned int)u) << 16; return v.f;
}
__device__ __forceinline__ ushort f2bf(float f){
    union { float f; unsigned int i; } v; v.f = f;
    unsigned int x = v.i;
    return (ushort)((x + 0x7FFFu + ((x >> 16) & 1u)) >> 16);  // RNE, inputs finite
}

// ---------------------------------------------------------------------------
// Kernel 0: dtype detector (flag=1 -> bf16 data, flag=0 -> float32).
// ---------------------------------------------------------------------------
__global__ void detect_kernel(const unsigned int* __restrict__ feat_raw, int* __restrict__ flag){
    __shared__ int cnt_s;
    if (threadIdx.x == 0) cnt_s = 0;
    __syncthreads();
    int c = 0;
    for (int i = threadIdx.x; i < 4096; i += 256){
        unsigned int w = feat_raw[i];
        unsigned int e = (w >> 7) & 0xFFu;
        if (e >= 100u && e <= 150u) c++;
    }
    atomicAdd(&cnt_s, c);
    __syncthreads();
    if (threadIdx.x == 0) *flag = (cnt_s > 2457) ? 1 : 0;
}

// ---------------------------------------------------------------------------
// Kernel 1: per-batch span offsets. offs[b][0..8]; counts[k] = max(n-k-2, 0).
// ---------------------------------------------------------------------------
__global__ void offs_kernel(const int* __restrict__ mask, int* __restrict__ offs){
    int b = blockIdx.x;
    int lane = threadIdx.x;
    int s = 0;
    for (int i = lane; i < LL; i += 64) s += mask[b*LL + i];
    #pragma unroll
    for (int d = 32; d > 0; d >>= 1) s += __shfl_down(s, d, 64);
    if (lane == 0){
        int n = s, cum = 0;
        offs[b*9 + 0] = 0;
        for (int j = 0; j < 8; ++j){
            int c = n - j - 2; if (c < 0) c = 0;
            cum += c;
            offs[b*9 + j + 1] = cum;
        }
    }
}

// ---------------------------------------------------------------------------
// Kernel 1b: flattened-M row maps per width bucket.
// amap[kk][r] = featbf word-row of first window token; omap[kk][r] = out slot.
// pfx[kk*33+32] = Mtot for that bucket.
// ---------------------------------------------------------------------------
__global__ void maps_kernel(const int* __restrict__ offs, int* __restrict__ pfx,
                            int* __restrict__ amap, int* __restrict__ omap){
    const int kkidx = blockIdx.x;
    const int kk = kkidx + 2;
    __shared__ int P[33];
    __shared__ int base_s[32];
    const int tid = threadIdx.x;
    if (tid == 0){
        int acc = 0; P[0] = 0;
        for (int b = 0; b < 32; ++b){
            acc += offs[b*9 + kk] - offs[b*9 + kk - 1];
            P[b+1] = acc;
        }
    }
    if (tid < 32) base_s[tid] = offs[tid*9 + kk - 1];
    __syncthreads();
    if (tid == 0) pfx[kkidx*33 + 32] = P[32];
    const int Mtot = P[32];
    for (int r = tid; r < MAXM; r += 256){
        int b = 0;
        #pragma unroll
        for (int i = 1; i <= 32; ++i) b += (P[i] <= r) ? 1 : 0;
        int bb = b < 32 ? b : 31;
        int larow = (r < Mtot) ? (r - P[bb]) : 0;   // clamp OOB rows to a safe row
        amap[kkidx*MAXM + r] = bb*LL + larow + 1;
        omap[kkidx*MAXM + r] = bb*SS + base_s[bb] + larow;
    }
}

// ---------------------------------------------------------------------------
// Kernel 2: ALL widths' weight repack in ONE launch. grid=(192, 7).
// w_kk [768][768][kk] (O,I,T) -> Bp_kk[jb][o][jj], j=jb*8+jj=t*768+i.
// Bias -> biasF (float) by ob==0 blocks.
// ---------------------------------------------------------------------------
__global__ void repack2_kernel(const void* __restrict__ w2, const void* __restrict__ w3,
                               const void* __restrict__ w4, const void* __restrict__ w5,
                               const void* __restrict__ w6, const void* __restrict__ w7,
                               const void* __restrict__ w8,
                               const void* __restrict__ b2, const void* __restrict__ b3,
                               const void* __restrict__ b4, const void* __restrict__ b5,
                               const void* __restrict__ b6, const void* __restrict__ b7,
                               const void* __restrict__ b8,
                               ushort* __restrict__ BpAll, float* __restrict__ biasF,
                               const int* __restrict__ flag){
    const size_t PRE[7] = {0, 2, 5, 9, 14, 20, 27};
    const int kkidx = blockIdx.y;
    const int kk = kkidx + 2;
    const void* w  = kkidx==0?w2:kkidx==1?w3:kkidx==2?w4:kkidx==3?w5:kkidx==4?w6:kkidx==5?w7:w8;
    const void* bv = kkidx==0?b2:kkidx==1?b3:kkidx==2?b4:kkidx==3?b5:kkidx==4?b6:kkidx==5?b7:b8;
    ushort* Bp = BpAll + PRE[kkidx]*589824;

    const int bfm = *flag;
    __shared__ ushort lds[24576];         // 4 rows x 768*8 max (49152 B)
    const int tid = threadIdx.x;
    const int ob  = blockIdx.x;           // 4 output channels each
    const int rowlen = DD * kk;
    const int nelem  = 4 * rowlen;

    if (bfm){
        const ushort* src = (const ushort*)w + (size_t)ob * nelem;
        const int nch = nelem >> 3;
        for (int c = tid; c < nch; c += 256)
            __builtin_memcpy(lds + c*8, src + c*8, 16);
        if (ob == 0)
            for (int i = tid; i < DD; i += 256) biasF[kkidx*DD + i] = bf2f(((const ushort*)bv)[i]);
    } else {
        const float* src = (const float*)w + (size_t)ob * nelem;
        const int nch = nelem >> 2;
        for (int c = tid; c < nch; c += 256){
            float t4[4];
            __builtin_memcpy(t4, src + c*4, 16);
            #pragma unroll
            for (int j2 = 0; j2 < 4; ++j2) lds[c*4 + j2] = f2bf(t4[j2]);
        }
        if (ob == 0)
            for (int i = tid; i < DD; i += 256) biasF[kkidx*DD + i] = ((const float*)bv)[i];
    }
    __syncthreads();

    const int total = 96 * kk * 4;
    for (int c = tid; c < total; c += 256){
        int jb = c >> 2, ol = c & 3;
        int j0 = jb * 8;
        int t  = j0 / 768;
        int i0 = j0 - t * 768;
        ushort tmp[8];
        #pragma unroll
        for (int jj = 0; jj < 8; ++jj)
            tmp[jj] = lds[ol*rowlen + (i0 + jj)*kk + t];
        int o = ob*4 + ol;
        __builtin_memcpy(Bp + (size_t)jb*6144 + (size_t)o*8, tmp, 16);
    }
}

// ---------------------------------------------------------------------------
// Kernel 2b: features -> bf16 A-source buffer.
// ---------------------------------------------------------------------------
__global__ void cvtA_kernel(const void* __restrict__ feat, ushort* __restrict__ featbf,
                            const int* __restrict__ flag){
    const int bfm = *flag;
    int idx = blockIdx.x*256 + threadIdx.x;
    const int TOT = BB*LL*DD/8;
    if (idx >= TOT) return;
    if (bfm){
        __builtin_memcpy(featbf + (size_t)idx*8, (const ushort*)feat + (size_t)idx*8, 16);
    } else {
        float t8[8];
        __builtin_memcpy(t8,     (const float*)feat + (size_t)idx*8,     16);
        __builtin_memcpy(t8 + 4, (const float*)feat + (size_t)idx*8 + 4, 16);
        ushort o8[8];
        #pragma unroll
        for (int j = 0; j < 8; ++j) o8[j] = f2bf(t8[j]);
        __builtin_memcpy(featbf + (size_t)idx*8, o8, 16);
    }
}

// ---------------------------------------------------------------------------
// Kernel 3: unigram copy + zero invalid + valid flags (native dtype).
// ---------------------------------------------------------------------------
__global__ void fill_kernel(const void* __restrict__ feat, const int* __restrict__ offs,
                            void* __restrict__ out, const int* __restrict__ flag){
    const int bfm = *flag;
    int idx = blockIdx.x*256 + threadIdx.x;
    const int TOT = BB*SS*192;
    if (idx >= TOT) return;
    int b = idx / (SS*192);
    int r = idx - b*(SS*192);
    int s = r / 192;
    int c = r - s*192;
    int c0  = offs[b*9 + 1];
    int tot = offs[b*9 + 8];
    if (bfm){
        if (c < 96){
            ushort* dst = (ushort*)out + ((size_t)b*SS + s)*768 + c*8;
            if (s < c0){
                const ushort* srcp = (const ushort*)feat + ((size_t)b*LL + s + 1)*768 + c*8;
                __builtin_memcpy(dst, srcp, 16);
            } else if (s >= tot){
                const ushort z[8] = {0,0,0,0,0,0,0,0};
                __builtin_memcpy(dst, z, 16);
            }
        }
        if (c == 0)
            ((ushort*)out)[(size_t)BB*SS*768 + (size_t)b*SS + s] = (s < tot) ? (ushort)0x3F80 : (ushort)0;
    } else {
        float* dst = (float*)out + ((size_t)b*SS + s)*768 + c*4;
        if (s < c0){
            const float* srcp = (const float*)feat + ((size_t)b*LL + s + 1)*768 + c*4;
            __builtin_memcpy(dst, srcp, 16);
        } else if (s >= tot){
            const float z[4] = {0.f,0.f,0.f,0.f};
            __builtin_memcpy(dst, z, 16);
        }
        if (c == 0)
            ((float*)out)[(size_t)BB*SS*768 + (size_t)b*SS + s] = (s < tot) ? 1.0f : 0.0f;
    }
}

// ---------------------------------------------------------------------------
// Kernel 4: flattened-M 128x128-tile GEMM, LDS-staged B (BK=64), 2x2 waves.
// grid.x = nt*50 + mt (mt fast -> consecutive blocks share the B chunk in L2),
// grid.y = kkidx. A rows via amap (per-lane direct loads; X is L2-resident).
// ---------------------------------------------------------------------------
__global__ __launch_bounds__(256) void conv_gemm2(const ushort* __restrict__ featbf,
        const ushort* __restrict__ BpAll, const float* __restrict__ biasF,
        const int* __restrict__ pfx, const int* __restrict__ amap,
        const int* __restrict__ omap, void* __restrict__ out,
        const int* __restrict__ flag){
    const size_t PRE[7] = {0, 2, 5, 9, 14, 20, 27};
    const int kkidx = blockIdx.y;
    const int kk = kkidx + 2;
    const int Mtot = pfx[kkidx*33 + 32];
    const int nt = blockIdx.x / 50;
    const int mt = blockIdx.x - nt*50;
    const int m0 = mt * 128;
    if (m0 >= Mtot) return;
    const int n0 = nt * 128;
    const int bfm = *flag;

    __shared__ ushort Bs[8192];           // 16 KB: 8 planes x 128 cols x 8 shorts

    const int tid  = threadIdx.x;
    const int wv   = tid >> 6;
    const int wvm  = wv >> 1;             // wave row (0..1)
    const int wvn  = wv & 1;              // wave col (0..1)
    const int lane = tid & 63;
    const int quad = lane >> 4;
    const int l15  = lane & 15;

    // A row base pointers for the 4 m-subtiles of this wave-row
    const ushort* Abase[4];
    #pragma unroll
    for (int sm = 0; sm < 4; ++sm){
        int r = kkidx*MAXM + m0 + wvm*64 + sm*16 + l15;
        Abase[sm] = featbf + (size_t)amap[r]*768 + quad*8;
    }

    floatx4 acc[4][4];
    #pragma unroll
    for (int sn = 0; sn < 4; ++sn){
        float bv = biasF[kkidx*768 + n0 + wvn*64 + sn*16 + l15];
        #pragma unroll
        for (int sm = 0; sm < 4; ++sm){
            acc[sm][sn][0] = bv; acc[sm][sn][1] = bv;
            acc[sm][sn][2] = bv; acc[sm][sn][3] = bv;
        }
    }

    const ushort* BkkBase = BpAll + PRE[kkidx]*589824;
    const int nchunks = kk * 12;          // K / 64

    for (int ch = 0; ch < nchunks; ++ch){
        // ---- stage B chunk: planes jb0..jb0+7, cols n0..n0+127 (16 KB) ----
        const int jb0 = ch*8;
        ushort stg[4][8];
        #pragma unroll
        for (int i = 0; i < 4; ++i){
            int c = i*256 + tid;
            int p = c >> 7, off = c & 127;
            const ushort* g = BkkBase + (size_t)(jb0 + p)*6144 + (size_t)(n0 + off)*8;
            __builtin_memcpy(stg[i], g, 16);
        }
        // ---- prefetch A for both K-steps (global; overlaps barrier wait) ----
        bf16x8 afr[2][4];
        const int koff = ch*64;
        #pragma unroll
        for (int ks = 0; ks < 2; ++ks)
            #pragma unroll
            for (int sm = 0; sm < 4; ++sm)
                __builtin_memcpy(&afr[ks][sm], Abase[sm] + koff + ks*32, 16);

        #pragma unroll
        for (int i = 0; i < 4; ++i)
            __builtin_memcpy(Bs + (i*256 + tid)*8, stg[i], 16);
        __syncthreads();

        #pragma unroll
        for (int ks = 0; ks < 2; ++ks){
            const int pl = ks*4 + quad;
            bf16x8 bfr[4];
            #pragma unroll
            for (int sn = 0; sn < 4; ++sn)
                __builtin_memcpy(&bfr[sn], Bs + pl*1024 + (wvn*64 + sn*16 + l15)*8, 16);
            #pragma unroll
            for (int sm = 0; sm < 4; ++sm)
                #pragma unroll
                for (int sn = 0; sn < 4; ++sn)
                    acc[sm][sn] = __builtin_amdgcn_mfma_f32_16x16x32_bf16(
                        afr[ks][sm], bfr[sn], acc[sm][sn], 0, 0, 0);
        }
        __syncthreads();
    }

    // ---- epilogue: scatter rows to packed span slots ----
    #pragma unroll
    for (int sm = 0; sm < 4; ++sm){
        #pragma unroll
        for (int rr = 0; rr < 4; ++rr){
            int r = m0 + wvm*64 + sm*16 + quad*4 + rr;
            if (r < Mtot){
                int slot = omap[kkidx*MAXM + r];
                if (bfm){
                    ushort* oh = (ushort*)out;
                    #pragma unroll
                    for (int sn = 0; sn < 4; ++sn)
                        oh[(size_t)slot*768 + n0 + wvn*64 + sn*16 + l15] = f2bf(acc[sm][sn][rr]);
                } else {
                    float* of = (float*)out;
                    #pragma unroll
                    for (int sn = 0; sn < 4; ++sn)
                        of[(size_t)slot*768 + n0 + wvn*64 + sn*16 + l15] = acc[sm][sn][rr];
                }
            }
        }
    }
}

// ---------------------------------------------------------------------------
// Fallback (workspace too small): direct-from-raw-weights GEMM. Slow, correct.
// ---------------------------------------------------------------------------
__global__ __launch_bounds__(256) void conv_gemm_direct(const void* __restrict__ feat,
        const int* __restrict__ offs, void* __restrict__ out, const int* __restrict__ flag,
        const void* w2, const void* w3, const void* w4, const void* w5,
        const void* w6, const void* w7, const void* w8,
        const void* b2, const void* b3, const void* b4, const void* b5,
        const void* b6, const void* b7, const void* b8){
    const int bfm = *flag;
    const int kkidx = blockIdx.y;
    const int kk = kkidx + 2;
    const int b = blockIdx.z;
    const void* w  = kkidx==0?w2:kkidx==1?w3:kkidx==2?w4:kkidx==3?w5:kkidx==4?w6:kkidx==5?w7:w8;
    const void* bv = kkidx==0?b2:kkidx==1?b3:kkidx==2?b4:kkidx==3?b5:kkidx==4?b6:kkidx==5?b7:b8;

    const int off_j = offs[b*9 + kk - 1];
    const int cnt   = offs[b*9 + kk] - off_j;
    const int mt = blockIdx.x / 12;
    const int nt = blockIdx.x - mt*12;
    const int m0 = mt * 64;
    if (m0 >= cnt) return;
    const int n0 = nt * 64;

    const int tid  = threadIdx.x;
    const int wvv  = tid >> 6;
    const int lane = tid & 63;
    const int quad = lane >> 4;
    const int l15  = lane & 15;

    int row  = m0 + wvv*16 + l15;
    int arow = row < cnt ? row : cnt - 1;
    const size_t abase = ((size_t)b*LL + arow + 1)*768 + quad*8;

    floatx4 acc[4];
    #pragma unroll
    for (int cg = 0; cg < 4; ++cg){
        float bb = bfm ? bf2f(((const ushort*)bv)[n0 + cg*16 + l15])
                       : ((const float*)bv)[n0 + cg*16 + l15];
        acc[cg][0] = bb; acc[cg][1] = bb; acc[cg][2] = bb; acc[cg][3] = bb;
    }

    const int steps = kk * 24;
    for (int s = 0; s < steps; ++s){
        bf16x8 a;
        if (bfm){
            __builtin_memcpy(&a, (const ushort*)feat + abase + s*32, 16);
        } else {
            float t8[8];
            __builtin_memcpy(t8,     (const float*)feat + abase + s*32,     16);
            __builtin_memcpy(t8 + 4, (const float*)feat + abase + s*32 + 4, 16);
            ushort o8[8];
            #pragma unroll
            for (int j = 0; j < 8; ++j) o8[j] = f2bf(t8[j]);
            __builtin_memcpy(&a, o8, 16);
        }
        int j0 = s*32 + quad*8;
        int t  = j0 / 768;
        int i0 = j0 - t*768;
        #pragma unroll
        for (int cg = 0; cg < 4; ++cg){
            int o = n0 + cg*16 + l15;
            size_t wbase = (size_t)o*(DD*kk) + (size_t)i0*kk + t;
            ushort tmp[8];
            if (bfm){
                const ushort* wp = (const ushort*)w + wbase;
                #pragma unroll
                for (int jj = 0; jj < 8; ++jj) tmp[jj] = wp[(size_t)jj*kk];
            } else {
                const float* wp = (const float*)w + wbase;
                #pragma unroll
                for (int jj = 0; jj < 8; ++jj) tmp[jj] = f2bf(wp[(size_t)jj*kk]);
            }
            bf16x8 bfr;
            __builtin_memcpy(&bfr, tmp, 16);
            acc[cg] = __builtin_amdgcn_mfma_f32_16x16x32_bf16(a, bfr, acc[cg], 0, 0, 0);
        }
    }

    const int rbase = m0 + wvv*16 + quad*4;
    if (bfm){
        ushort* outh = (ushort*)out;
        #pragma unroll
        for (int cg = 0; cg < 4; ++cg)
            #pragma unroll
            for (int rr = 0; rr < 4; ++rr){
                int grow = rbase + rr;
                if (grow < cnt)
                    outh[((size_t)b*SS + off_j + grow)*768 + n0 + cg*16 + l15] = f2bf(acc[cg][rr]);
            }
    } else {
        float* outf = (float*)out;
        #pragma unroll
        for (int cg = 0; cg < 4; ++cg)
            #pragma unroll
            for (int rr = 0; rr < 4; ++rr){
                int grow = rbase + rr;
                if (grow < cnt)
                    outf[((size_t)b*SS + off_j + grow)*768 + n0 + cg*16 + l15] = acc[cg][rr];
            }
    }
}

// ---------------------------------------------------------------------------
extern "C" void kernel_launch(void* const* d_in, const int* in_sizes, int n_in,
                              void* d_out, int out_size, void* d_ws, size_t ws_size,
                              hipStream_t stream) {
    const void* feat = d_in[0];
    const int*  mask = (const int*)d_in[1];

    const void* w[7]  = {0,0,0,0,0,0,0};
    const void* bs[7] = {0,0,0,0,0,0,0};
    int bi = 0;
    for (int i = 3; i < n_in; ++i){
        if (in_sizes[i] == 768){
            if (bi < 7) bs[bi++] = d_in[i];
        } else {
            int kk = in_sizes[i] / 589824;
            if (kk >= 2 && kk <= 8) w[kk-2] = d_in[i];
        }
    }

    // ws layout
    char* ws = (char*)d_ws;
    int*    flag    = (int*)ws;                       // @0
    int*    offs    = (int*)(ws + 64);                // 1152 B
    int*    pfx     = (int*)(ws + 2048);              // 924 B
    float*  biasF   = (float*)(ws + 4096);            // 21504 B
    int*    amap    = (int*)(ws + 28672);             // 7*6400*4 = 179200
    int*    omap    = (int*)(ws + 28672 + 179200);    // 179200 -> end 387072
    ushort* featbf  = (ushort*)(ws + 393216);         // 9,830,400
    ushort* Bp      = (ushort*)(ws + 393216 + 9830400); // 41,287,680
    const size_t FULL_BYTES = 393216ull + 9830400ull + 41287680ull;  // 51,511,296
    const bool use_full = ws_size >= FULL_BYTES;

    hipLaunchKernelGGL(detect_kernel, dim3(1), dim3(256), 0, stream,
                       (const unsigned int*)feat, flag);
    hipLaunchKernelGGL(offs_kernel, dim3(BB), dim3(64), 0, stream, mask, offs);

    if (use_full){
        hipLaunchKernelGGL(repack2_kernel, dim3(192, 7), dim3(256), 0, stream,
                           w[0], w[1], w[2], w[3], w[4], w[5], w[6],
                           bs[0], bs[1], bs[2], bs[3], bs[4], bs[5], bs[6],
                           Bp, biasF, flag);
        hipLaunchKernelGGL(cvtA_kernel, dim3(2400), dim3(256), 0, stream, feat, featbf, flag);
        hipLaunchKernelGGL(maps_kernel, dim3(7), dim3(256), 0, stream, offs, pfx, amap, omap);
    }

    hipLaunchKernelGGL(fill_kernel, dim3((BB*SS*192 + 255)/256), dim3(256), 0, stream,
                       feat, offs, d_out, flag);

    if (use_full){
        hipLaunchKernelGGL(conv_gemm2, dim3(300, 7), dim3(256), 0, stream,
                           featbf, Bp, biasF, pfx, amap, omap, d_out, flag);
    } else {
        hipLaunchKernelGGL(conv_gemm_direct, dim3(48, 7, BB), dim3(256), 0, stream,
                           feat, offs, d_out, flag,
                           w[0], w[1], w[2], w[3], w[4], w[5], w[6],
                           bs[0], bs[1], bs[2], bs[3], bs[4], bs[5], bs[6]);
    }
}